// Round 3
// baseline (102.886 us; speedup 1.0000x reference)
//
#include <hip/hip_runtime.h>

// EulerRNNCell — Genois qubit SDE Euler-Maruyama rollout.
// B=512 batch, NUM_TRAJ=64 trajectories/batch, T-1=255 steps.
// One block (1 wave, 64 threads) per batch element; thread j runs
// trajectory n = j*512 + b; mean over 64 trajectories = wave shuffle reduce.
//
// Output layout (floats): [0,3584) = out[512,7] (probs ++ inputs).
// rho (complex64 [512,4]) is compared by the harness as float32 real parts
// (sz forced to 2048 by reshape(512,4)): real plane at [3584,5632).
// Imag plane written at [5632,7680) only if the buffer has room.

#define BATCH   512
#define NTRAJ   64
#define TSTEPS  255

__global__ __launch_bounds__(64) void euler_rollout_kernel(
    const float* __restrict__ inputs,   // [512,1]
    const float* __restrict__ bloch0,   // [3]
    const float* __restrict__ wvec,     // [32768, 255, 2]
    float* __restrict__ out,            // [out_size]
    int out_size)
{
    const int b = blockIdx.x;           // batch index
    const int j = threadIdx.x;          // trajectory replica 0..63
    const long long n = (long long)j * BATCH + b;

    const float omega = inputs[b] + 1e-8f;

    // constants, mirroring reference f32 values exactly
    const float HG = 0.55f;                       // 0.5 * GAMMA
    const float K  = 0.44497190922573976f;        // sqrt(GAMMA*ETA/2) = sqrt(0.198)
    const float SD = 0.0625f;                     // sqrt(DT) = 2^-4 (exact)
    const float DT = 0.00390625f;                 // 2^-8

    float x1 = bloch0[0];
    float x2 = bloch0[1];
    float x3 = bloch0[2];

    // row of 255 float2 noise pairs for this trajectory (8B aligned)
    const float2* __restrict__ wrow =
        reinterpret_cast<const float2*>(wvec) + n * TSTEPS;

    // Fully unrolled: all 255 loads are base+imm-offset, independent of the
    // x-chain, so the compiler hoists them deep ahead for latency hiding.
#pragma unroll
    for (int t = 0; t < TSTEPS; ++t) {
        const float2 w = wrow[t];
        const float d1 = w.x * SD;
        const float d2 = w.y * SD;

        const float ax = -HG * x1;
        const float ay = -omega * x3 - HG * x2;
        const float az = omega * x2;

        const float bx = K * (-x1 * x3 * d1 + x2 * d2);
        const float by = K * (-x2 * x3 * d1 - x1 * d2);
        const float bz = K * ((1.0f - x3 * x3) * d1);

        const float y1 = x1 + DT * ax + bx;
        const float y2 = x2 + DT * ay + by;
        const float y3 = x3 + DT * az + bz;
        x1 = y1; x2 = y2; x3 = y3;
    }

    // wave-wide sum over the 64 trajectories of this batch element
#pragma unroll
    for (int off = 32; off > 0; off >>= 1) {
        x1 += __shfl_xor(x1, off);
        x2 += __shfl_xor(x2, off);
        x3 += __shfl_xor(x3, off);
    }

    if (j == 0) {
        const float inv = 1.0f / (float)NTRAJ;
        const float xm1 = x1 * inv;
        const float xm2 = x2 * inv;
        const float xm3 = x3 * inv;

        float px = 0.5f * (xm1 + 1.0f);
        float py = 0.5f * (xm2 + 1.0f);
        float pz = 0.5f * (xm3 + 1.0f);

        float p0 = fminf(fmaxf(px, 0.0f), 1.0f);
        float p1 = fminf(fmaxf(1.0f - px, 0.0f), 1.0f);
        float p2 = fminf(fmaxf(py, 0.0f), 1.0f);
        float p3 = fminf(fmaxf(1.0f - py, 0.0f), 1.0f);
        float p4 = fminf(fmaxf(pz, 0.0f), 1.0f);
        float p5 = fminf(fmaxf(1.0f - pz, 0.0f), 1.0f);

        float* o = out + (long long)b * 7;
        o[0] = p0; o[1] = p1; o[2] = p2; o[3] = p3; o[4] = p4; o[5] = p5;
        o[6] = inputs[b];

        // rho real parts: [(1+z)/2, x/2, x/2, (1-z)/2] at [3584, 5632)
        float* rre = out + BATCH * 7 + (long long)b * 4;
        rre[0] = (1.0f + xm3) * 0.5f;
        rre[1] = xm1 * 0.5f;
        rre[2] = xm1 * 0.5f;
        rre[3] = (1.0f - xm3) * 0.5f;

        // rho imag parts: [0, -y/2, y/2, 0] at [5632, 7680) if buffer has room
        if (out_size >= BATCH * 7 + BATCH * 8) {
            float* rim = out + BATCH * 7 + BATCH * 4 + (long long)b * 4;
            rim[0] = 0.0f;
            rim[1] = -xm2 * 0.5f;
            rim[2] = xm2 * 0.5f;
            rim[3] = 0.0f;
        }
    }
}

extern "C" void kernel_launch(void* const* d_in, const int* in_sizes, int n_in,
                              void* d_out, int out_size, void* d_ws, size_t ws_size,
                              hipStream_t stream) {
    const float* inputs = (const float*)d_in[0];   // [512,1]
    const float* bloch0 = (const float*)d_in[1];   // [3]
    const float* wvec   = (const float*)d_in[2];   // [32768,255,2]
    float* out = (float*)d_out;

    euler_rollout_kernel<<<dim3(BATCH), dim3(64), 0, stream>>>(
        inputs, bloch0, wvec, out, out_size);
}